// Round 6
// baseline (64.268 us; speedup 1.0000x reference)
//
#include <hip/hip_runtime.h>
#include <hip/hip_bf16.h>

#define N_TOKENS   262144
#define DIM        64
#define KCODES     512
#define OUT_ELEMS  (N_TOKENS * DIM)          // 16777216
#define LOSS_SCALE (1.25f / 16777216.0f)

typedef float  f32x4 __attribute__((ext_vector_type(4)));
typedef float  f32x8 __attribute__((ext_vector_type(8)));
typedef short  s16x8 __attribute__((ext_vector_type(8)));

static __device__ __forceinline__ unsigned short f2bf(float f) {
    unsigned int u = __builtin_bit_cast(unsigned int, f);
    u += 0x7fffu + ((u >> 16) & 1u);          // round-to-nearest-even
    return (unsigned short)(u >> 16);
}

// Prep: codebook -> bf16(-2c) in MFMA-fragment order (ws), ||c||^2+2 (ws), zero loss.
// Fragment element index for (code k, dim d):
//   t=k>>4, li=k&15, kk=d>>5, hi=(d>>3)&3, j=d&7 -> ((t*2+kk)*64 + hi*16+li)*8 + j
// +2 bias keeps every distance key strictly positive so uint cmp == float cmp.
__global__ void vq_prep(const float* __restrict__ cb,
                        unsigned short* __restrict__ cbf,
                        float* __restrict__ c2,
                        float* __restrict__ out_loss) {
    const int k = blockIdx.x;       // 512 blocks, one code each
    const int d = threadIdx.x;      // 64 threads (one wave)
    const float v = cb[k * DIM + d];
    float s = v * v;
    #pragma unroll
    for (int sh = 1; sh < 64; sh <<= 1) s += __shfl_xor(s, sh, 64);
    if (d == 0) c2[k] = s + 2.0f;

    const int t = k >> 4, li = k & 15;
    const int kk = d >> 5, hi = (d >> 3) & 3, j = d & 7;
    const int slot = (t * 2 + kk) * 64 + hi * 16 + li;
    cbf[slot * 8 + j] = f2bf(-2.0f * v);

    if (k == 0 && d == 0) *out_loss = 0.0f;
}

// B-fragment load for column-tile T, k-half KK (lane-linear, 1 KB/wave-instr)
#define LOADB(T, KK) (*(const s16x8*)(cbf + (((T) * 2 + (KK)) * 64 + lane) * 8))

// Main: 4 waves x 32 tokens = 128 tokens/block, 2048 blocks -> 8192 waves
// = 32 waves/CU (HW max). TLP does the latency hiding; no explicit pipelining.
// m=2 working set (~55 VGPR) genuinely fits the 64-VGPR/8-wave budget
// (round 3 spilled because m=4's ~90-reg set was forced under the same cap).
__global__ __launch_bounds__(256, 8) void vq_main(
    const float* __restrict__ z,
    const float* __restrict__ cb,              // fp32 codebook (exact gather)
    const unsigned short* __restrict__ cbf,    // bf16(-2c), fragment order
    const float* __restrict__ c2g,             // ||c||^2 + 2
    float* __restrict__ out)
{
    __shared__ int   keysl[4][32];
    __shared__ float lpart[4];

    const int tid  = threadIdx.x;
    const int wave = tid >> 6;
    const int lane = tid & 63;
    const int li   = lane & 15;   // A-row / C-col lane index
    const int hi   = lane >> 4;   // k-group

    const int token0 = blockIdx.x * 128 + wave * 32;

    // ---- load z, build bf16 A-fragments, compute ||z||^2 per row ----
    s16x8 af[2][2];
    float z2[2];
    #pragma unroll
    for (int m = 0; m < 2; ++m) {
        float zs = 0.f;
        #pragma unroll
        for (int kk = 0; kk < 2; ++kk) {
            const float* p = z + (size_t)(token0 + m * 16 + li) * DIM + kk * 32 + hi * 8;
            const f32x8 v = *(const f32x8*)p;
            s16x8 a;
            #pragma unroll
            for (int j = 0; j < 8; ++j) {
                zs += v[j] * v[j];
                a[j] = (short)f2bf(v[j]);
            }
            af[m][kk] = a;
        }
        zs += __shfl_xor(zs, 16, 64);
        zs += __shfl_xor(zs, 32, 64);
        z2[m] = zs;   // full row sum, replicated across the hi-group
    }

    // ---- argmin over 512 codes; B-fragments streamed from L2 ----
    unsigned bkey[2][4];
    #pragma unroll
    for (int m = 0; m < 2; ++m)
        #pragma unroll
        for (int r = 0; r < 4; ++r) bkey[m][r] = 0xFFFFFFFFu;

    #pragma unroll 4
    for (int t = 0; t < 32; ++t) {
        const s16x8 b0 = LOADB(t, 0);
        const s16x8 b1 = LOADB(t, 1);
        const float cv = c2g[t * 16 + li];
        const unsigned code = (unsigned)(t * 16 + li);
        #pragma unroll
        for (int m = 0; m < 2; ++m) {
            f32x4 acc = {cv, cv, cv, cv};
            acc = __builtin_amdgcn_mfma_f32_16x16x32_bf16(af[m][0], b0, acc, 0, 0, 0);
            acc = __builtin_amdgcn_mfma_f32_16x16x32_bf16(af[m][1], b1, acc, 0, 0, 0);
            // acc[r] = ||c||^2 + 2 - 2 z.c for row (m*16 + hi*4 + r), col code
            #pragma unroll
            for (int r = 0; r < 4; ++r) {
                const unsigned key = (__builtin_bit_cast(unsigned, acc[r]) & ~511u) | code;
                if (key < bkey[m][r]) bkey[m][r] = key;   // v_and_or + v_min_u32
            }
        }
    }

    // ---- reduce across the 16 li-lanes (positive-float keys: uint min) ----
    #pragma unroll
    for (int sh = 1; sh < 16; sh <<= 1) {
        #pragma unroll
        for (int m = 0; m < 2; ++m)
            #pragma unroll
            for (int r = 0; r < 4; ++r) {
                const unsigned ok = (unsigned)__shfl_xor((int)bkey[m][r], sh, 64);
                if (ok < bkey[m][r]) bkey[m][r] = ok;
            }
    }

    // rows m*16 + hi*4 + r -> key; per-wave private LDS slab (no barrier needed)
    if (li == 0) {
        #pragma unroll
        for (int m = 0; m < 2; ++m)
            #pragma unroll
            for (int r = 0; r < 4; ++r)
                keysl[wave][m * 16 + hi * 4 + r] = (int)bkey[m][r];
    }

    // ---- gather exact fp32 rows, write z_q, loss from winning key + ||z||^2 ----
    float lossp = 0.f;
    #pragma unroll
    for (int m = 0; m < 2; ++m) {
        const unsigned key = (unsigned)keysl[wave][m * 16 + li];   // row = m*16+li
        const int code = (int)(key & 511u);
        if (hi == 0)
            lossp += (__builtin_bit_cast(float, key & ~511u) - 2.0f) + z2[m];
        const float* cbr = cb + code * DIM + hi * 8;
        const f32x8 q0 = *(const f32x8*)(cbr);
        const f32x8 q1 = *(const f32x8*)(cbr + 32);
        float* op = out + (size_t)(token0 + m * 16 + li) * DIM + hi * 8;
        *(f32x8*)(op)      = q0;
        *(f32x8*)(op + 32) = q1;
    }
    #pragma unroll
    for (int sh = 1; sh < 64; sh <<= 1) lossp += __shfl_xor(lossp, sh, 64);
    if (lane == 0) lpart[wave] = lossp;
    __syncthreads();
    if (tid == 0) {
        float s = lpart[0] + lpart[1] + lpart[2] + lpart[3];
        atomicAdd(out + OUT_ELEMS, s * LOSS_SCALE);
    }
}

extern "C" void kernel_launch(void* const* d_in, const int* in_sizes, int n_in,
                              void* d_out, int out_size, void* d_ws, size_t ws_size,
                              hipStream_t stream) {
    const float* z  = (const float*)d_in[0];
    const float* cb = (const float*)d_in[1];
    float* out = (float*)d_out;

    unsigned short* cbf = (unsigned short*)d_ws;                               // 64 KiB
    float* c2 = (float*)((char*)d_ws + KCODES * DIM * sizeof(unsigned short)); // 2 KiB

    vq_prep<<<KCODES, 64, 0, stream>>>(cb, cbf, c2, out + OUT_ELEMS);
    vq_main<<<N_TOKENS / 128, 256, 0, stream>>>(z, cb, cbf, c2, out);
}

// Round 7
// 36.383 us; speedup vs baseline: 1.7664x; 1.7664x over previous
//
#include <hip/hip_runtime.h>
#include <hip/hip_bf16.h>

#define N_TOKENS   262144
#define DIM        64
#define KCODES     512
#define OUT_ELEMS  (N_TOKENS * DIM)          // 16777216
#define LOSS_SCALE (1.25f / 16777216.0f)

typedef float  f32x4 __attribute__((ext_vector_type(4)));
typedef float  f32x8 __attribute__((ext_vector_type(8)));
typedef short  s16x8 __attribute__((ext_vector_type(8)));
typedef unsigned short u16x8 __attribute__((ext_vector_type(8)));

static __device__ __forceinline__ unsigned short f2bf(float f) {
    unsigned int u = __builtin_bit_cast(unsigned int, f);
    u += 0x7fffu + ((u >> 16) & 1u);          // round-to-nearest-even
    return (unsigned short)(u >> 16);
}

// Prep: codebook -> bf16(-2c) in MFMA-fragment order (ws), ||c||^2+2 (ws), zero loss.
// Fragment element index for (code k, dim d):
//   t=k>>4, li=k&15, kk=d>>5, hi=(d>>3)&3, j=d&7 -> ((t*2+kk)*64 + hi*16+li)*8 + j
// +2 bias keeps every distance key strictly positive so uint cmp == float cmp.
__global__ void vq_prep(const float* __restrict__ cb,
                        unsigned short* __restrict__ cbf,
                        float* __restrict__ c2,
                        float* __restrict__ out_loss) {
    const int k = blockIdx.x;       // 512 blocks, one code each
    const int d = threadIdx.x;      // 64 threads (one wave)
    const float v = cb[k * DIM + d];
    float s = v * v;
    #pragma unroll
    for (int sh = 1; sh < 64; sh <<= 1) s += __shfl_xor(s, sh, 64);
    if (d == 0) c2[k] = s + 2.0f;

    const int t = k >> 4, li = k & 15;
    const int kk = d >> 5, hi = (d >> 3) & 3, j = d & 7;
    const int slot = (t * 2 + kk) * 64 + hi * 16 + li;
    cbf[slot * 8 + j] = f2bf(-2.0f * v);

    if (k == 0 && d == 0) *out_loss = 0.0f;
}

// Main: 256 blocks x 1024 threads (16 waves). Each block stages the 64 KiB
// fragment-ordered bf16 codebook into LDS ONCE (amortized over 1024 tokens),
// then each wave independently runs 2x 32-token tiles with NO further
// block-wide barriers -> waves desynchronize and overlap each other's
// z-loads / MFMA / gathers / writes. m=2 keeps VGPR ~<=64 so LDS (70 KiB,
// 2 blocks/CU) and VGPR both allow 32 waves/CU.
// NOTE: min-waves>=8 in launch_bounds spilled in R3/R6 (gfx950 allocator
// over-constrains under the unified VGPR/AGPR file) -> use (1024, 4).
__global__ __launch_bounds__(1024, 4) void vq_main(
    const float* __restrict__ z,
    const float* __restrict__ cb,              // fp32 codebook (exact gather)
    const unsigned short* __restrict__ cbf,    // bf16(-2c), fragment order
    const float* __restrict__ c2g,             // ||c||^2 + 2
    float* __restrict__ out)
{
    __shared__ unsigned short cbs[KCODES * DIM];   // 64 KiB, fragment order
    __shared__ float c2s[KCODES];                  // 2 KiB
    __shared__ int   keysl[16][32];                // 2 KiB
    __shared__ float lpart[16];

    const int tid  = threadIdx.x;
    const int wave = tid >> 6;
    const int lane = tid & 63;
    const int li   = lane & 15;   // A-row / C-col lane index
    const int hi   = lane >> 4;   // k-group

    // ---- stage fragment-ordered codebook: pure linear copy, conflict-free ----
    #pragma unroll
    for (int i = 0; i < 4; ++i)
        ((u16x8*)cbs)[i * 1024 + tid] = ((const u16x8*)cbf)[i * 1024 + tid];
    if (tid < KCODES) c2s[tid] = c2g[tid];
    __syncthreads();   // the ONLY block-wide barrier before the loss epilogue

    float lossp = 0.f;

    #pragma unroll
    for (int tt = 0; tt < 2; ++tt) {
        const int token0 = blockIdx.x * 1024 + wave * 64 + tt * 32;

        // ---- load z, build bf16 A-fragments, ||z||^2 per row ----
        s16x8 af[2][2];
        float z2[2];
        #pragma unroll
        for (int m = 0; m < 2; ++m) {
            float zs = 0.f;
            #pragma unroll
            for (int kk = 0; kk < 2; ++kk) {
                const float* p = z + (size_t)(token0 + m * 16 + li) * DIM + kk * 32 + hi * 8;
                const f32x8 v = *(const f32x8*)p;
                s16x8 a;
                #pragma unroll
                for (int j = 0; j < 8; ++j) {
                    zs += v[j] * v[j];
                    a[j] = (short)f2bf(v[j]);
                }
                af[m][kk] = a;
            }
            zs += __shfl_xor(zs, 16, 64);
            zs += __shfl_xor(zs, 32, 64);
            z2[m] = zs;
        }

        // ---- argmin over 512 codes; B-fragments from LDS ----
        unsigned bkey[2][4];
        #pragma unroll
        for (int m = 0; m < 2; ++m)
            #pragma unroll
            for (int r = 0; r < 4; ++r) bkey[m][r] = 0xFFFFFFFFu;

        #pragma unroll 4
        for (int t = 0; t < 32; ++t) {
            const s16x8 b0 = *(const s16x8*)&cbs[((t * 2 + 0) * 64 + lane) * 8];
            const s16x8 b1 = *(const s16x8*)&cbs[((t * 2 + 1) * 64 + lane) * 8];
            const float cv = c2s[t * 16 + li];
            const unsigned code = (unsigned)(t * 16 + li);
            #pragma unroll
            for (int m = 0; m < 2; ++m) {
                f32x4 acc = {cv, cv, cv, cv};
                acc = __builtin_amdgcn_mfma_f32_16x16x32_bf16(af[m][0], b0, acc, 0, 0, 0);
                acc = __builtin_amdgcn_mfma_f32_16x16x32_bf16(af[m][1], b1, acc, 0, 0, 0);
                // acc[r] = ||c||^2 + 2 - 2 z.c for row (m*16 + hi*4 + r), col code
                #pragma unroll
                for (int r = 0; r < 4; ++r) {
                    const unsigned key = (__builtin_bit_cast(unsigned, acc[r]) & ~511u) | code;
                    if (key < bkey[m][r]) bkey[m][r] = key;   // v_and_or + v_min_u32
                }
            }
        }

        // ---- reduce across the 16 li-lanes (positive-float keys: uint min) ----
        #pragma unroll
        for (int sh = 1; sh < 16; sh <<= 1) {
            #pragma unroll
            for (int m = 0; m < 2; ++m)
                #pragma unroll
                for (int r = 0; r < 4; ++r) {
                    const unsigned ok = (unsigned)__shfl_xor((int)bkey[m][r], sh, 64);
                    if (ok < bkey[m][r]) bkey[m][r] = ok;
                }
        }

        // rows m*16 + hi*4 + r -> key; wave-private slab, no barrier needed
        if (li == 0) {
            #pragma unroll
            for (int m = 0; m < 2; ++m)
                #pragma unroll
                for (int r = 0; r < 4; ++r)
                    keysl[wave][m * 16 + hi * 4 + r] = (int)bkey[m][r];
        }

        // ---- gather exact fp32 rows (L2-hit), write z_q, loss from key ----
        #pragma unroll
        for (int m = 0; m < 2; ++m) {
            const unsigned key = (unsigned)keysl[wave][m * 16 + li];  // row = m*16+li
            const int code = (int)(key & 511u);
            if (hi == 0)
                lossp += (__builtin_bit_cast(float, key & ~511u) - 2.0f) + z2[m];
            const float* cbr = cb + code * DIM + hi * 8;
            const f32x8 q0 = *(const f32x8*)(cbr);
            const f32x8 q1 = *(const f32x8*)(cbr + 32);
            float* op = out + (size_t)(token0 + m * 16 + li) * DIM + hi * 8;
            *(f32x8*)(op)      = q0;
            *(f32x8*)(op + 32) = q1;
        }
    }

    // ---- loss reduction: wave shuffle -> per-wave slot -> single atomic ----
    #pragma unroll
    for (int sh = 1; sh < 64; sh <<= 1) lossp += __shfl_xor(lossp, sh, 64);
    if (lane == 0) lpart[wave] = lossp;
    __syncthreads();
    if (tid == 0) {
        float s = 0.f;
        #pragma unroll
        for (int w = 0; w < 16; ++w) s += lpart[w];
        atomicAdd(out + OUT_ELEMS, s * LOSS_SCALE);
    }
}

extern "C" void kernel_launch(void* const* d_in, const int* in_sizes, int n_in,
                              void* d_out, int out_size, void* d_ws, size_t ws_size,
                              hipStream_t stream) {
    const float* z  = (const float*)d_in[0];
    const float* cb = (const float*)d_in[1];
    float* out = (float*)d_out;

    unsigned short* cbf = (unsigned short*)d_ws;                               // 64 KiB
    float* c2 = (float*)((char*)d_ws + KCODES * DIM * sizeof(unsigned short)); // 2 KiB

    vq_prep<<<KCODES, 64, 0, stream>>>(cb, cbf, c2, out + OUT_ELEMS);
    vq_main<<<N_TOKENS / 1024, 1024, 0, stream>>>(z, cb, cbf, c2, out);
}